// Round 1
// 164.092 us; speedup vs baseline: 1.0587x; 1.0587x over previous
//
#include <hip/hip_runtime.h>
#include <math.h>

#define NTOK 8192
#define DD   2048
#define EE   64
#define TSTRIP 16            // tokens per block (one MFMA m-tile)
#define NCH 16               // chunks per K-half (64 d each)
#define PROB_N (NTOK*2)
#define AROW 136             // 128 feats + 8 pad (halves); 272B rows, 16B aligned
// F layout: [plane:2][ck:128][nt:4][lane:64][j:8] fp16 = 1 MB
#define F_PSTRIDE (128*4*64*8)

typedef _Float16 f16x8 __attribute__((ext_vector_type(8)));
typedef _Float16 f16x4 __attribute__((ext_vector_type(4)));
typedef float    f32x4 __attribute__((ext_vector_type(4)));

// fast branchless atan2 (Cephes reduction + deg-7 odd minimax), ~3e-7 abs
__device__ __forceinline__ float fast_atan2f(float y, float x) {
    const float ax = __builtin_fabsf(x), ay = __builtin_fabsf(y);
    const float hi = fmaxf(ax, ay), lo = fminf(ax, ay);
    const bool  big = lo > 0.4142135679721832f * hi;       // tan(pi/8)
    const float num = big ? (lo - hi) : lo;
    const float den = big ? (lo + hi) : hi;
    float rc = __builtin_amdgcn_rcpf(den);
    rc = rc * fmaf(-den, rc, 2.0f);                        // 1 NR step
    const float z  = num * rc;
    const float z2 = z * z;
    float p = fmaf(z2, 8.05374449538e-2f, -1.38776856032e-1f);
    p = fmaf(z2, p, 1.99777106478e-1f);
    p = fmaf(z2, p, -3.33329491539e-1f);
    float r = fmaf(z * z2, p, z);
    r = r + (big ? 0.78539816339744830962f : 0.0f);
    r = (ay > ax) ? (1.57079632679489661923f - r) : r;
    r = (x < 0.0f) ? (3.14159265358979323846f - r) : r;
    return copysignf(r, y);
}

// fp16 2-split with scaled low plane: x ~= h1 + h2s*2^-11, err ~2^-24|x|
__device__ __forceinline__ void fsplit2(float x, _Float16& h1, _Float16& h2s) {
    const _Float16 a = (_Float16)x;                 // RNE, 11 bits
    h1 = a;
    h2s = (_Float16)((x - (float)a) * 2048.0f);     // next ~12 bits, normal-scaled
}

// Kernel 0: split W [4096][64] fp32 -> F fragment-order fp16 (2 planes, 1 MB)
__global__ __launch_bounds__(256) void wsplit(const float* __restrict__ W,
                                              _Float16* __restrict__ F) {
    const int g  = blockIdx.x * 256 + threadIdx.x;   // 32768 threads
    const int e  = g & 63;
    const int q  = g >> 6;          // 0..511
    const int d0 = q * 4;
    const int nt = e >> 4;
    const int lane = ((d0 & 31) >> 3) * 16 + (e & 15);
    const int j0 = d0 & 7;          // 0 or 4
    const int cka = 2 * (d0 >> 5);  // amp kstep; phase kstep = cka+1

    f16x4 a1, a2, p1, p2;
    #pragma unroll
    for (int i = 0; i < 4; ++i) {
        _Float16 h, l;
        fsplit2(W[(size_t)(d0 + i) * EE + e], h, l);      a1[i] = h; a2[i] = l;
        fsplit2(W[(size_t)(DD + d0 + i) * EE + e], h, l); p1[i] = h; p2[i] = l;
    }
    *(f16x4*)&F[((size_t)(0 * 128 + cka)     * 4 + nt) * 512 + lane * 8 + j0] = a1;
    *(f16x4*)&F[((size_t)(1 * 128 + cka)     * 4 + nt) * 512 + lane * 8 + j0] = a2;
    *(f16x4*)&F[((size_t)(0 * 128 + cka + 1) * 4 + nt) * 512 + lane * 8 + j0] = p1;
    *(f16x4*)&F[((size_t)(1 * 128 + cka + 1) * 4 + nt) * 512 + lane * 8 + j0] = p2;
}

// Kernel 1: fully fused. Block = 16 tokens, full K. 8 waves = 4 expert-tiles
// x 2 K-halves. Double-buffered LDS A (amp/phase split once per element),
// register-double-buffered B prefetch (chunk c+1 issued during chunk c),
// raw s_barrier + lgkmcnt(0) only -- B/x loads stay in flight across the
// barrier (T4: never drain vmcnt to 0 in the main loop).
__global__ __launch_bounds__(512, 4) void gemm_topk(
    const float* __restrict__ xr, const float* __restrict__ xi,
    const _Float16* __restrict__ F, const float* __restrict__ bias,
    float* __restrict__ out)
{
    __shared__ __align__(16) _Float16 A[2][2][2][TSTRIP][AROW];  // 34 KB
    __shared__ float scoreH[2][TSTRIP][EE];                       // 8 KB

    const int tid = threadIdx.x;
    const int t0  = blockIdx.x * TSTRIP;
    // compute roles
    const int wv = tid >> 6, lane = tid & 63;
    const int nt = wv & 3, kh = wv >> 2;
    const int fm = lane & 15, fq = lane >> 4;
    // staging roles
    const int kh_s  = tid >> 8;
    const int tok_s = (tid >> 4) & 15;
    const int f4    = tid & 15;

    const float bv = bias[lane];

    const float* prx = xr + (size_t)(t0 + tok_s) * DD + kh_s * 1024 + f4 * 4;
    const float* pix = xi + (size_t)(t0 + tok_s) * DD + kh_s * 1024 + f4 * 4;
    const int posa = 64 * (f4 >> 3) + (f4 & 7) * 4;   // amp slot; phase = +32

    auto sprocess = [&](float4 vr, float4 vi, int buf) {
        const float ar[4] = {vr.x, vr.y, vr.z, vr.w};
        const float ai[4] = {vi.x, vi.y, vi.z, vi.w};
        f16x4 a1, a2, p1, p2;
        #pragma unroll
        for (int i = 0; i < 4; ++i) {
            const float amp = __builtin_amdgcn_sqrtf(fmaf(ar[i], ar[i], ai[i] * ai[i]));
            const float ph  = fast_atan2f(ai[i], ar[i]);
            _Float16 h, l;
            fsplit2(amp, h, l); a1[i] = h; a2[i] = l;
            fsplit2(ph,  h, l); p1[i] = h; p2[i] = l;
        }
        *(f16x4*)&A[buf][kh_s][0][tok_s][posa]      = a1;
        *(f16x4*)&A[buf][kh_s][1][tok_s][posa]      = a2;
        *(f16x4*)&A[buf][kh_s][0][tok_s][posa + 32] = p1;
        *(f16x4*)&A[buf][kh_s][1][tok_s][posa + 32] = p2;
    };

    f32x4 accH = (f32x4){0.f, 0.f, 0.f, 0.f};
    f32x4 accL = (f32x4){0.f, 0.f, 0.f, 0.f};

    // per-wave B base: chunk c lives at bbase + c*8192 elements
    const _Float16* bbase = F + ((size_t)(kh * 64) * 4 + nt) * 512 + lane * 8;

    // register double-buffer for B fragments; all indices compile-time static
    // via full unroll (rule #20: no runtime-indexed ext_vector arrays)
    f16x8 bh[2][4], bl[2][4];

    // prologue: issue x(0) first (so its wait leaves B(0) in flight),
    // then B(0), then stage chunk 0 into LDS A[0]
    {
        const float4 vr0 = *(const float4*)prx;
        const float4 vi0 = *(const float4*)pix;
        #pragma unroll
        for (int j = 0; j < 4; ++j) {
            bh[0][j] = *(const f16x8*)(bbase + j * 2048);
            bl[0][j] = *(const f16x8*)(bbase + F_PSTRIDE + j * 2048);
        }
        sprocess(vr0, vi0, 0);
    }
    asm volatile("s_waitcnt lgkmcnt(0)" ::: "memory");
    __builtin_amdgcn_s_barrier();
    asm volatile("" ::: "memory");

    #pragma unroll
    for (int c = 0; c < NCH; ++c) {
        const int buf  = c & 1;
        const int nbuf = buf ^ 1;
        const bool more = (c + 1 < NCH);
        float4 nvr, nvi;
        if (more) {
            // x prefetch first (oldest -> its wait keeps B(c+1) in flight)
            nvr = *(const float4*)(prx + (c + 1) * 64);
            nvi = *(const float4*)(pix + (c + 1) * 64);
            // B prefetch for chunk c+1 into the other register buffer
            const _Float16* nb = bbase + (size_t)(c + 1) * 8192;
            #pragma unroll
            for (int j = 0; j < 4; ++j) {
                bh[nbuf][j] = *(const f16x8*)(nb + j * 2048);
                bl[nbuf][j] = *(const f16x8*)(nb + F_PSTRIDE + j * 2048);
            }
        }
        // MFMA on current chunk; compiler inserts counted vmcnt for bh/bl[buf]
        // (prefetched a full chunk + barrier ago) and lgkmcnt for A reads
        #pragma unroll
        for (int j = 0; j < 4; ++j) {
            const f16x8 a1 = *(const f16x8*)&A[buf][kh][0][fm][j * 32 + fq * 8];
            const f16x8 a2 = *(const f16x8*)&A[buf][kh][1][fm][j * 32 + fq * 8];
            accH = __builtin_amdgcn_mfma_f32_16x16x32_f16(a1, bh[buf][j], accH, 0, 0, 0);
            accL = __builtin_amdgcn_mfma_f32_16x16x32_f16(a1, bl[buf][j], accL, 0, 0, 0);
            accL = __builtin_amdgcn_mfma_f32_16x16x32_f16(a2, bh[buf][j], accL, 0, 0, 0);
        }
        if (more) {
            // stage chunk c+1 (waits x only -> vmcnt(8): B(c+1) stays in flight)
            sprocess(nvr, nvi, nbuf);
            // raw barrier: drain LDS ops only; global loads cross the barrier
            asm volatile("s_waitcnt lgkmcnt(0)" ::: "memory");
            __builtin_amdgcn_s_barrier();
            asm volatile("" ::: "memory");
        }
    }

    // D layout: col(expert-in-tile)=lane&15, row(token)=(lane>>4)*4+reg [m89]
    #pragma unroll
    for (int r = 0; r < 4; ++r)
        scoreH[kh][fq * 4 + r][nt * 16 + fm] = fmaf(accL[r], 4.8828125e-4f, accH[r]);
    __syncthreads();

    // exact top-2 (tie-break lower index, matching lax.top_k); 2 tokens/wave
    #pragma unroll
    for (int rep = 0; rep < 2; ++rep) {
        const int tok = wv * 2 + rep;
        float v1 = scoreH[0][tok][lane] + scoreH[1][tok][lane] + bv;
        float v2 = -INFINITY;
        int   i1 = lane, i2 = 64;
        #pragma unroll
        for (int off = 1; off < 64; off <<= 1) {
            const float ov1 = __shfl_xor(v1, off, 64);
            const int   oi1 = __shfl_xor(i1, off, 64);
            const float ov2 = __shfl_xor(v2, off, 64);
            const int   oi2 = __shfl_xor(i2, off, 64);
            const bool b1 = (ov1 > v1) || (ov1 == v1 && oi1 < i1);
            const float n1 = b1 ? ov1 : v1;  const int ni1 = b1 ? oi1 : i1;
            const float c1 = b1 ? v1  : ov1; const int ci1 = b1 ? i1  : oi1;
            const float c2 = b1 ? ov2 : v2;  const int ci2 = b1 ? oi2 : i2;
            const bool b2 = (c1 > c2) || (c1 == c2 && ci1 < ci2);
            v1 = n1; i1 = ni1;
            v2 = b2 ? c1 : c2; i2 = b2 ? ci1 : ci2;
        }
        if (lane == 0) {
            const int t = t0 + tok;
            const float z  = expf(v2 - v1);
            const float p1 = 1.0f / (1.0f + z);
            const float p2 = z / (1.0f + z);
            out[(size_t)t * 2 + 0] = p1;
            out[(size_t)t * 2 + 1] = p2;
            out[PROB_N + (size_t)t * 2 + 0] = (float)i1;
            out[PROB_N + (size_t)t * 2 + 1] = (float)i2;
        }
    }
}

extern "C" void kernel_launch(void* const* d_in, const int* in_sizes, int n_in,
                              void* d_out, int out_size, void* d_ws, size_t ws_size,
                              hipStream_t stream) {
    const float* xr = (const float*)d_in[0];
    const float* xi = (const float*)d_in[1];
    const float* W  = (const float*)d_in[2];
    const float* b  = (const float*)d_in[3];
    float* out = (float*)d_out;
    _Float16* F = (_Float16*)d_ws;   // 1 MB swizzled 2-plane fp16 W

    wsplit<<<128, 256, 0, stream>>>(W, F);
    gemm_topk<<<NTOK / TSTRIP, 512, 0, stream>>>(xr, xi, F, b, out);
}